// Round 1
// baseline (281.827 us; speedup 1.0000x reference)
//
#include <hip/hip_runtime.h>
#include <stdint.h>

#define PTS 256                 // threads per block; one point per thread
#define DIM 10

// Codebook as compile-time constant. Every use below is fully unrolled and
// constant-folds: the dot loop folds to an add/sub chain, the mask table folds
// to inline cndmask constants. No runtime indexing -> no rodata gather.
static constexpr float CB[32][10] = {
 {-1,-1,-1,-1,-1,-1,-1,-1,-1,-1},{-1,-1,-1,-1,1,1,-1,-1,-1,1},{-1,-1,-1,1,-1,-1,-1,-1,1,1},{-1,-1,-1,1,1,1,-1,-1,1,-1},
 {-1,-1,1,-1,-1,-1,-1,1,1,-1},{-1,-1,1,-1,1,1,-1,1,1,1},{-1,-1,1,1,-1,-1,-1,1,-1,1},{-1,-1,1,1,1,1,-1,1,-1,-1},
 {-1,1,-1,-1,-1,-1,1,1,-1,-1},{-1,1,-1,-1,1,1,1,1,-1,1},{-1,1,-1,1,-1,-1,1,1,1,1},{-1,1,-1,1,1,1,1,1,1,-1},
 {-1,1,1,-1,-1,-1,1,-1,1,-1},{-1,1,1,-1,1,1,1,-1,1,1},{-1,1,1,1,-1,-1,1,-1,-1,1},{-1,1,1,1,1,1,1,-1,-1,-1},
 {1,-1,-1,-1,-1,1,1,-1,-1,-1},{1,-1,-1,-1,1,-1,1,-1,-1,1},{1,-1,-1,1,-1,1,1,-1,1,1},{1,-1,-1,1,1,-1,1,-1,1,-1},
 {1,-1,1,-1,-1,1,1,1,1,-1},{1,-1,1,-1,1,-1,1,1,1,1},{1,-1,1,1,-1,1,1,1,-1,1},{1,-1,1,1,1,-1,1,1,-1,-1},
 {1,1,-1,-1,-1,1,-1,1,-1,-1},{1,1,-1,-1,1,-1,-1,1,-1,1},{1,1,-1,1,-1,1,-1,1,1,1},{1,1,-1,1,1,-1,-1,1,1,-1},
 {1,1,1,-1,-1,1,-1,-1,1,-1},{1,1,1,-1,1,-1,-1,-1,1,1},{1,1,1,1,-1,1,-1,-1,-1,1},{1,1,1,1,1,-1,-1,-1,-1,-1}};

// 10-bit sign mask per codeword, derived at compile time from CB
// (bit j set iff CB[k][j] == +1). Avoids hand-transcription errors.
struct CBMasks { uint32_t m[32]; };
static constexpr CBMasks make_masks() {
    CBMasks r{};
    for (int k = 0; k < 32; ++k) {
        uint32_t mm = 0;
        for (int j = 0; j < DIM; ++j)
            if (CB[k][j] > 0.0f) mm |= (1u << j);
        r.m[k] = mm;
    }
    return r;
}
static constexpr CBMasks CBM = make_masks();

__global__ __launch_bounds__(PTS) void softdec_kernel(
    const float* __restrict__ sig, float* __restrict__ out)
{
    // One point (10 floats, 40 B, 8-B aligned) per thread. No LDS, no barriers.
    const size_t p = (size_t)blockIdx.x * PTS + threadIdx.x;

    // ---- load: 5x global_load_dwordx2, offsets fold into imm ----
    const float2* __restrict__ gp = (const float2*)sig + p * 5;
    float x[DIM];
    #pragma unroll
    for (int q = 0; q < 5; ++q) {
        const float2 v = gp[q];
        x[2 * q]     = v.x;
        x[2 * q + 1] = v.y;
    }

    // ---- 32 signed sums + argmax. IDENTICAL summation order and strict-'>'
    // tie rule as the previous passing kernel (bit-identical numerics). ----
    float    best = -1e30f;
    uint32_t bm   = 0u;                      // mask of codeword 0 (all -1)
    #pragma unroll
    for (int k = 0; k < 32; ++k) {
        float s = 0.0f;
        #pragma unroll
        for (int j = 0; j < DIM; ++j)
            s = (CB[k][j] > 0.0f) ? (s + x[j]) : (s - x[j]);   // folds to add/sub
        if (s > best) { best = s; bm = CBM.m[k]; }             // folds to cmp+cndmask
    }

    // ---- reconstruct +-1.0f from mask bits: +1.0f=0x3F800000, -1.0f=0xBF800000,
    // differ only in bit 31. 3 VALU per element, no memory gather. ----
    float2* __restrict__ op = (float2*)out + p * 5;
    #pragma unroll
    for (int q = 0; q < 5; ++q) {
        float2 v;
        v.x = __uint_as_float(0xBF800000u ^ (((bm >> (2 * q))     & 1u) << 31));
        v.y = __uint_as_float(0xBF800000u ^ (((bm >> (2 * q + 1)) & 1u) << 31));
        op[q] = v;                            // 5x global_store_dwordx2
    }
}

extern "C" void kernel_launch(void* const* d_in, const int* in_sizes, int n_in,
                              void* d_out, int out_size, void* d_ws, size_t ws_size,
                              hipStream_t stream) {
    const float* sig = (const float*)d_in[0];
    float* out = (float*)d_out;
    const int total  = in_sizes[0];        // B*N*D = 41,943,040 floats
    const int pts    = total / DIM;        // 4,194,304 points
    const int blocks = pts / PTS;          // 16,384 blocks (exact)
    softdec_kernel<<<blocks, PTS, 0, stream>>>(sig, out);
}